// Round 3
// baseline (479.192 us; speedup 1.0000x reference)
//
#include <hip/hip_runtime.h>
#include <hip/hip_bf16.h>

// Problem: B=32, C=256, CM=32, L=4096.  Inputs fp32, output fp32.
// V4: MFMA rewrite of both conv passes (they are GEMMs: [32,256]x[256,L]
// and [256,32]x[32,L]).  V1-V3 were instruction-soup-bound (per-iter weight
// loads + shuffle-max + AGPR-resident accumulators); occupancy was maxed at
// V3 with no gain.  MFMA holds weights in pre-swizzled A-fragments (built by
// k_fold, loaded once per block) and accumulates in native MFMA AGPRs.
// k-mapping trick: A and B operand slots pair by identical (lane>>4, j)
// k-layout, so any self-consistent k-bijection works; we use k = 8*(lane>>4)+j
// so both fragment fetches are contiguous 16B.
// C/D layout (HW-verified m89): col = lane&15, row = (lane>>4)*4 + reg.
// h stored [b][l][m] bf16 so pass2 B-frags are direct coalesced global loads.
// No CSPLIT / no partials / no combine kernel: full K=256 per block.

#define NB 32
#define NC 256
#define NM 32
#define NL 4096
#define BNEPS 1e-5f

#define LT1 128      // pass1: l per block
#define KST 128      // pass1: c per LDS stage (2 stages)
#define LDW 132      // pass1 LDS row width in u16 (128 + 4 pad)
#define LT2 64       // pass2: l per block

typedef unsigned int u32;
typedef unsigned short u16;
typedef __attribute__((ext_vector_type(8))) short bf16x8;  // 8 bf16 = 4 VGPR
typedef __attribute__((ext_vector_type(4))) float f32x4;   // mfma acc

// workspace layout (float offsets)
#define OFF_AF1  0                     // u16[8192] w1 A-frags (2mt x 8q x 64lane x 8)
#define OFF_AF2  (OFF_AF1 + 4096)     // u16[8192] w2 A-frags (16ct x 64lane x 8)
#define OFF_B1F  (OFF_AF2 + 4096)     // f32[NM]   folded bias1
#define OFF_B2F  (OFF_B1F + NM)       // f32[NC]   folded bias2
#define OFF_GW1T (OFF_B2F + NC)       // f32[NC*NM] global-branch w1 (fp32, exact)
#define OFF_GB1F (OFF_GW1T + NC*NM)   // f32[NM]
#define OFF_GW2T (OFF_GB1F + NM)      // f32[NM*NC]
#define OFF_GB2F (OFF_GW2T + NM*NC)   // f32[NC]
#define OFF_AC   (OFF_GB2F + NC)      // f32[NB*NC]  b2f[c] + ga[b][c]
#define OFF_GMAX (OFF_AC + NB*NC)     // u32[NB*NC]  encoded-float max
#define OFF_HC   (OFF_GMAX + NB*NC)   // bf16 [NB][NL][NM]  (8 MiB)

__device__ __forceinline__ unsigned f2u_mono(float f) {
    unsigned u = __float_as_uint(f);
    return (u & 0x80000000u) ? ~u : (u | 0x80000000u);
}
__device__ __forceinline__ float u2f_mono(unsigned u) {
    return (u & 0x80000000u) ? __uint_as_float(u & 0x7fffffffu)
                             : __uint_as_float(~u);
}
__device__ __forceinline__ u16 f2bf(float a) {
    return __bfloat16_as_ushort(__float2bfloat16(a));
}
__device__ __forceinline__ float bf2f(u16 a) {
    return __uint_as_float(((u32)a) << 16);
}
__device__ __forceinline__ u32 pack2(float a, float b) {
    return (u32)f2bf(a) | ((u32)f2bf(b) << 16);
}

// ---------------- kernel A: fold BN into weights; build MFMA A-frags --------
__global__ __launch_bounds__(256) void k_fold(
    const float* __restrict__ lw1, const float* __restrict__ lb1,
    const float* __restrict__ lg1, const float* __restrict__ lbe1,
    const float* __restrict__ lm1, const float* __restrict__ lv1,
    const float* __restrict__ lw2, const float* __restrict__ lb2,
    const float* __restrict__ lg2, const float* __restrict__ lbe2,
    const float* __restrict__ lm2, const float* __restrict__ lv2,
    const float* __restrict__ gw1, const float* __restrict__ gb1,
    const float* __restrict__ gg1, const float* __restrict__ gbe1,
    const float* __restrict__ gm1, const float* __restrict__ gv1,
    const float* __restrict__ gw2, const float* __restrict__ gb2,
    const float* __restrict__ gg2, const float* __restrict__ gbe2,
    const float* __restrict__ gm2, const float* __restrict__ gv2,
    float* __restrict__ ws) {
    u16* af1   = (u16*)(ws + OFF_AF1);
    u16* af2   = (u16*)(ws + OFF_AF2);
    float* b1f  = ws + OFF_B1F;  float* b2f  = ws + OFF_B2F;
    float* gw1t = ws + OFF_GW1T; float* gb1f = ws + OFF_GB1F;
    float* gw2t = ws + OFF_GW2T; float* gb2f = ws + OFF_GB2F;
    unsigned* gmaxU = (unsigned*)(ws + OFF_GMAX);

    int tid = blockIdx.x * blockDim.x + threadIdx.x;
    int nt  = gridDim.x * blockDim.x;

    // pass1 A-fragments: idx = ((mt*8+q)*64 + lane)*8 + j
    // element = w1[m= 16mt + (lane&15)][c = 32q + 8*(lane>>4) + j] * inv1[m]
    for (int i = tid; i < 8192; i += nt) {
        int j = i & 7, lane = (i >> 3) & 63, q = (i >> 9) & 7, mt = i >> 12;
        int m = 16 * mt + (lane & 15);
        int c = 32 * q + 8 * (lane >> 4) + j;
        float inv = lg1[m] * rsqrtf(lv1[m] + BNEPS);
        af1[i] = f2bf(lw1[m * NC + c] * inv);
    }
    // pass2 A-fragments: idx = (ct*64 + lane)*8 + j
    // element = w2[cout = 16ct + (lane&15)][m = 8*(lane>>4) + j] * inv2[cout]
    for (int i = tid; i < 8192; i += nt) {
        int j = i & 7, lane = (i >> 3) & 63, ct = i >> 9;
        int cout = 16 * ct + (lane & 15);
        int m = 8 * (lane >> 4) + j;
        float inv = lg2[cout] * rsqrtf(lv2[cout] + BNEPS);
        af2[i] = f2bf(lw2[cout * NM + m] * inv);
    }
    // global-branch folded weights (fp32, exact math as before)
    for (int i = tid; i < NC * NM; i += nt) {
        int c = i >> 5, m = i & 31;
        float gi1 = gg1[m] * rsqrtf(gv1[m] + BNEPS);
        gw1t[c * NM + m] = gw1[m * NC + c] * gi1;
        float gi2 = gg2[c] * rsqrtf(gv2[c] + BNEPS);
        gw2t[m * NC + c] = gw2[c * NM + m] * gi2;
    }
    for (int i = tid; i < NM; i += nt) {
        float inv = lg1[i] * rsqrtf(lv1[i] + BNEPS);
        b1f[i] = lb1[i] * inv + lbe1[i] - lm1[i] * inv;
        float gi = gg1[i] * rsqrtf(gv1[i] + BNEPS);
        gb1f[i] = gb1[i] * gi + gbe1[i] - gm1[i] * gi;
    }
    for (int i = tid; i < NC; i += nt) {
        float inv = lg2[i] * rsqrtf(lv2[i] + BNEPS);
        b2f[i] = lb2[i] * inv + lbe2[i] - lm2[i] * inv;
        float gi = gg2[i] * rsqrtf(gv2[i] + BNEPS);
        gb2f[i] = gb2[i] * gi + gbe2[i] - gm2[i] * gi;
    }
    for (int i = tid; i < NB * NC; i += nt) gmaxU[i] = 0u;  // below all floats
}

// ---------------- kernel B: conv1x1 #1 via MFMA + channel max ---------------
// grid (NL/LT1=32, NB) = 1024 blocks, 256 thr (4 waves) -> 4 blocks/CU.
// Per block: h[32, 128l] = W1[32,256] * V[256, 128l], V = bf16(x+y).
// LDS: V staged [cc][l] (c-major rows, +4 u16 pad), 2 stages of 128 c.
__global__ __launch_bounds__(256, 4) void k_pass1(
    const float4* __restrict__ x4, const float4* __restrict__ y4,
    const u16* __restrict__ af1, const float* __restrict__ b1f,
    unsigned* __restrict__ gmaxU, u16* __restrict__ hc) {
    __shared__ u16 vt[KST * LDW];     // 33.8 KB
    __shared__ float cmax[256];
    int b   = blockIdx.y;
    int l0  = blockIdx.x * LT1;
    int tid = threadIdx.x;
    int w = tid >> 6, lane = tid & 63, g = lane >> 4, li = lane & 15;

    // A-fragments: 2 m-tiles x 8 k-chunks, 16B coalesced each
    bf16x8 a1[2][8];
#pragma unroll
    for (int mt = 0; mt < 2; ++mt)
#pragma unroll
        for (int q = 0; q < 8; ++q)
            a1[mt][q] = *(const bf16x8*)(af1 + (((mt * 8 + q) * 64) + lane) * 8);

    f32x4 acc[2][2];
#pragma unroll
    for (int mt = 0; mt < 2; ++mt)
#pragma unroll
        for (int t = 0; t < 2; ++t) {
            f32x4 z = {0.f, 0.f, 0.f, 0.f};
            acc[mt][t] = z;
        }

    int hw = tid >> 5;   // 0..7: row-in-group for staging
    int lq = tid & 31;   // l-quad index (covers 128 l as float4)

#pragma unroll
    for (int s = 0; s < 2; ++s) {
        // ---- stage 128c x 128l tile into LDS (bf16, transposed to [c][l]) --
#pragma unroll 4
        for (int it = 0; it < 16; ++it) {
            int cc = it * 8 + hw;
            int c  = s * KST + cc;
            size_t ridx = ((size_t)(b * NC + c)) * (NL / 4) + (l0 / 4) + lq;
            float4 xv = x4[ridx];
            float4 yv = y4[ridx];
            float v0 = xv.x + yv.x, v1 = xv.y + yv.y;
            float v2 = xv.z + yv.z, v3 = xv.w + yv.w;
            uint2 wv;
            wv.x = pack2(v0, v1);
            wv.y = pack2(v2, v3);
            *(uint2*)&vt[cc * LDW + 4 * lq] = wv;
        }
        __syncthreads();

        // ---- MFMA: 4 k-chunks of 32, each wave does 2 l-tiles x 2 m-tiles --
#pragma unroll
        for (int qq = 0; qq < 4; ++qq)
#pragma unroll
            for (int t = 0; t < 2; ++t) {
                int lcol = 32 * w + 16 * t + li;
                bf16x8 bf;
#pragma unroll
                for (int j = 0; j < 8; ++j)
                    bf[j] = (short)vt[(32 * qq + 8 * g + j) * LDW + lcol];
                acc[0][t] = __builtin_amdgcn_mfma_f32_16x16x32_bf16(
                    a1[0][s * 4 + qq], bf, acc[0][t], 0, 0, 0);
                acc[1][t] = __builtin_amdgcn_mfma_f32_16x16x32_bf16(
                    a1[1][s * 4 + qq], bf, acc[1][t], 0, 0, 0);
            }

        // ---- channel max from the staged tile (bf16 values) ---------------
        {
            int cc = tid & 127, half = tid >> 7;
            float mx = -3.402823466e38f;
            int base = cc * LDW + half * 64;
#pragma unroll 8
            for (int l = 0; l < 64; ++l)
                mx = fmaxf(mx, bf2f(vt[base + l]));
            cmax[tid] = mx;
        }
        __syncthreads();   // also protects vt before next stage overwrite
        if (tid < 128)
            atomicMax(&gmaxU[b * NC + s * KST + tid],
                      f2u_mono(fmaxf(cmax[tid], cmax[tid + 128])));
    }

    // ---- epilogue: bias + ReLU + bf16, store h as [b][l][m] ----------------
#pragma unroll
    for (int mt = 0; mt < 2; ++mt)
#pragma unroll
        for (int t = 0; t < 2; ++t) {
            int l  = l0 + 32 * w + 16 * t + li;
            int m0 = 16 * mt + 4 * g;
            float h0 = fmaxf(acc[mt][t][0] + b1f[m0 + 0], 0.f);
            float h1 = fmaxf(acc[mt][t][1] + b1f[m0 + 1], 0.f);
            float h2 = fmaxf(acc[mt][t][2] + b1f[m0 + 2], 0.f);
            float h3 = fmaxf(acc[mt][t][3] + b1f[m0 + 3], 0.f);
            uint2 st;
            st.x = pack2(h0, h1);
            st.y = pack2(h2, h3);
            *(uint2*)&hc[((size_t)b * NL + l) * NM + m0] = st;
        }
}

// ---------------- kernel C: global branch (maxpool -> FC -> FC) -------------
__global__ __launch_bounds__(256) void k_global(
    const float* __restrict__ gw1t, const float* __restrict__ gb1f,
    const float* __restrict__ gw2t, const float* __restrict__ gb2f,
    const float* __restrict__ b2f, const unsigned* __restrict__ gmaxU,
    float* __restrict__ ac) {
    __shared__ float smax[NC];
    __shared__ float g1[NM];
    int b = blockIdx.x;
    int t = threadIdx.x;
    smax[t] = u2f_mono(gmaxU[b * NC + t]);
    __syncthreads();
    if (t < NM) {
        float a = gb1f[t];
        for (int c = 0; c < NC; ++c) a = fmaf(gw1t[c * NM + t], smax[c], a);
        g1[t] = fmaxf(a, 0.f);
    }
    __syncthreads();
    float a = b2f[t] + gb2f[t];
#pragma unroll
    for (int m = 0; m < NM; ++m) a = fmaf(gw2t[m * NC + t], g1[m], a);
    ac[b * NC + t] = a;  // = b2f[c] + ga[b][c]
}

// ---------------- kernel D: conv1x1 #2 via MFMA + sigmoid + blend -----------
// grid (NL/LT2=64, NB) = 2048 blocks, 256 thr.  No LDS staging: B-frags are
// direct coalesced 16B loads from hc[b][l][m].  Wave w owns couts 64w..64w+63.
__global__ __launch_bounds__(256, 4) void k_pass2(
    const float* __restrict__ x, const float* __restrict__ y,
    const u16* __restrict__ af2, const float* __restrict__ ac,
    const u16* __restrict__ hc, float* __restrict__ out) {
    __shared__ float acl[NC];
    int b   = blockIdx.y;
    int l0  = blockIdx.x * LT2;
    int tid = threadIdx.x;
    int w = tid >> 6, lane = tid & 63, g = lane >> 4, li = lane & 15;

    acl[tid] = ac[b * NC + tid];

    bf16x8 a2[4];
#pragma unroll
    for (int ct = 0; ct < 4; ++ct)
        a2[ct] = *(const bf16x8*)(af2 + ((w * 4 + ct) * 64 + lane) * 8);
    __syncthreads();

#pragma unroll 2
    for (int lt = 0; lt < 4; ++lt) {
        int l = l0 + 16 * lt + li;
        bf16x8 bfrag = *(const bf16x8*)(hc + ((size_t)b * NL + l) * NM + 8 * g);
        f32x4 acc[4];
#pragma unroll
        for (int ct = 0; ct < 4; ++ct) {
            f32x4 z = {0.f, 0.f, 0.f, 0.f};
            acc[ct] = __builtin_amdgcn_mfma_f32_16x16x32_bf16(
                a2[ct], bfrag, z, 0, 0, 0);
        }
#pragma unroll
        for (int ct = 0; ct < 4; ++ct)
#pragma unroll
            for (int r = 0; r < 4; ++r) {
                int cout = 64 * w + 16 * ct + 4 * g + r;
                float z = acc[ct][r] + acl[cout];
                float att = 1.f / (1.f + __expf(-z));
                size_t idx = ((size_t)(b * NC + cout)) * NL + l;
                float xv = x[idx];
                float yv = y[idx];
                float tt = yv + att * (xv - yv);
                out[idx] = tt + tt;  // 2*(y + att*(x-y))
            }
    }
}

extern "C" void kernel_launch(void* const* d_in, const int* in_sizes, int n_in,
                              void* d_out, int out_size, void* d_ws,
                              size_t ws_size, hipStream_t stream) {
    (void)in_sizes; (void)n_in; (void)out_size; (void)ws_size;
    const float* x = (const float*)d_in[0];
    const float* y = (const float*)d_in[1];
    float* ws  = (float*)d_ws;
    float* out = (float*)d_out;

    u16* af1   = (u16*)(ws + OFF_AF1);
    u16* af2   = (u16*)(ws + OFF_AF2);
    float* b1f  = ws + OFF_B1F;  float* b2f  = ws + OFF_B2F;
    float* gw1t = ws + OFF_GW1T; float* gb1f = ws + OFF_GB1F;
    float* gw2t = ws + OFF_GW2T; float* gb2f = ws + OFF_GB2F;
    float* ac   = ws + OFF_AC;
    unsigned* gmaxU = (unsigned*)(ws + OFF_GMAX);
    u16* hc = (u16*)(ws + OFF_HC);

    k_fold<<<64, 256, 0, stream>>>(
        (const float*)d_in[2],  (const float*)d_in[3],  (const float*)d_in[4],
        (const float*)d_in[5],  (const float*)d_in[6],  (const float*)d_in[7],
        (const float*)d_in[8],  (const float*)d_in[9],  (const float*)d_in[10],
        (const float*)d_in[11], (const float*)d_in[12], (const float*)d_in[13],
        (const float*)d_in[14], (const float*)d_in[15], (const float*)d_in[16],
        (const float*)d_in[17], (const float*)d_in[18], (const float*)d_in[19],
        (const float*)d_in[20], (const float*)d_in[21], (const float*)d_in[22],
        (const float*)d_in[23], (const float*)d_in[24], (const float*)d_in[25],
        ws);
    k_pass1<<<dim3(NL / LT1, NB), 256, 0, stream>>>(
        (const float4*)x, (const float4*)y, af1, b1f, gmaxU, hc);
    k_global<<<NB, 256, 0, stream>>>(gw1t, gb1f, gw2t, gb2f, b2f, gmaxU, ac);
    k_pass2<<<dim3(NL / LT2, NB), 256, 0, stream>>>(
        x, y, af2, ac, hc, out);
}

// Round 4
// 448.236 us; speedup vs baseline: 1.0691x; 1.0691x over previous
//
#include <hip/hip_runtime.h>
#include <hip/hip_bf16.h>

// Problem: B=32, C=256, CM=32, L=4096.  Inputs fp32, output fp32.
// V5: conv2 fused into pass1 (k_conv computes z = la pre-sigmoid, bf16
// [B,C,L] via 2nd MFMA stage + LDS transpose for 256B-contiguous stores);
// k_blend is a pure coalesced streamer (x,y,z in / out).  R3 showed pass2
// at ideal traffic but only 3.26 TB/s due to 4x64B scattered segments from
// the MFMA C-layout epilogue -- blend now has zero scatter.
// z needs ~67MB ws; if ws_size is smaller, run two b=16 halves (33.7MB,
// proven safe: V2 used 40.2MB).

#define NB 32
#define NC 256
#define NM 32
#define NL 4096
#define BNEPS 1e-5f
#define LT1 128      // l per k_conv block
#define LDW 132      // V-stage LDS row width in u16 (128 + 4 pad)
#define HLW 40       // h LDS row width in u16 (32 + 8 pad; 80B = 16B-multiple)

typedef unsigned int u32;
typedef unsigned short u16;
typedef __attribute__((ext_vector_type(8))) short bf16x8;  // 8 bf16 = 4 VGPR
typedef __attribute__((ext_vector_type(4))) float f32x4;   // mfma acc

// workspace layout (float offsets)
#define OFF_AF1  0                    // u16[8192] w1 A-frags ((mt*8+q)*64+lane)*8+j
#define OFF_AF2  (OFF_AF1 + 4096)    // u16[8192] w2 A-frags (ct*64+lane)*8+j
#define OFF_B1F  (OFF_AF2 + 4096)    // f32[NM]
#define OFF_B2F  (OFF_B1F + NM)      // f32[NC]
#define OFF_GW1T (OFF_B2F + NC)      // f32[NC*NM]
#define OFF_GB1F (OFF_GW1T + NC*NM)  // f32[NM]
#define OFF_GW2T (OFF_GB1F + NM)     // f32[NM*NC]
#define OFF_GB2F (OFF_GW2T + NM*NC)  // f32[NC]
#define OFF_AC   (OFF_GB2F + NC)     // f32[NB*NC]  b2f[c] + ga[b][c]
#define OFF_GMAX (OFF_AC + NB*NC)    // u32[NB*NC]  encoded-float max
#define OFF_Z    (OFF_GMAX + NB*NC)  // bf16 [nbh][NC][NL]  (64MB full / 32MB half)

__device__ __forceinline__ unsigned f2u_mono(float f) {
    unsigned u = __float_as_uint(f);
    return (u & 0x80000000u) ? ~u : (u | 0x80000000u);
}
__device__ __forceinline__ float u2f_mono(unsigned u) {
    return (u & 0x80000000u) ? __uint_as_float(u & 0x7fffffffu)
                             : __uint_as_float(~u);
}
__device__ __forceinline__ u16 f2bf(float a) {
    return __bfloat16_as_ushort(__float2bfloat16(a));
}
__device__ __forceinline__ float bf2f(u16 a) {
    return __uint_as_float(((u32)a) << 16);
}
__device__ __forceinline__ u32 pack2(float a, float b) {
    return (u32)f2bf(a) | ((u32)f2bf(b) << 16);
}

// ---------------- kernel A: fold BN into weights; build MFMA A-frags --------
__global__ __launch_bounds__(256) void k_fold(
    const float* __restrict__ lw1, const float* __restrict__ lb1,
    const float* __restrict__ lg1, const float* __restrict__ lbe1,
    const float* __restrict__ lm1, const float* __restrict__ lv1,
    const float* __restrict__ lw2, const float* __restrict__ lb2,
    const float* __restrict__ lg2, const float* __restrict__ lbe2,
    const float* __restrict__ lm2, const float* __restrict__ lv2,
    const float* __restrict__ gw1, const float* __restrict__ gb1,
    const float* __restrict__ gg1, const float* __restrict__ gbe1,
    const float* __restrict__ gm1, const float* __restrict__ gv1,
    const float* __restrict__ gw2, const float* __restrict__ gb2,
    const float* __restrict__ gg2, const float* __restrict__ gbe2,
    const float* __restrict__ gm2, const float* __restrict__ gv2,
    float* __restrict__ ws) {
    u16* af1   = (u16*)(ws + OFF_AF1);
    u16* af2   = (u16*)(ws + OFF_AF2);
    float* b1f  = ws + OFF_B1F;  float* b2f  = ws + OFF_B2F;
    float* gw1t = ws + OFF_GW1T; float* gb1f = ws + OFF_GB1F;
    float* gw2t = ws + OFF_GW2T; float* gb2f = ws + OFF_GB2F;
    unsigned* gmaxU = (unsigned*)(ws + OFF_GMAX);

    int tid = blockIdx.x * blockDim.x + threadIdx.x;
    int nt  = gridDim.x * blockDim.x;

    // pass1 A-fragments: element = w1[m=16mt+(lane&15)][c=32q+8*(lane>>4)+j]
    for (int i = tid; i < 8192; i += nt) {
        int j = i & 7, lane = (i >> 3) & 63, q = (i >> 9) & 7, mt = i >> 12;
        int m = 16 * mt + (lane & 15);
        int c = 32 * q + 8 * (lane >> 4) + j;
        float inv = lg1[m] * rsqrtf(lv1[m] + BNEPS);
        af1[i] = f2bf(lw1[m * NC + c] * inv);
    }
    // pass2 A-fragments: element = w2[cout=16ct+(lane&15)][m=8*(lane>>4)+j]
    for (int i = tid; i < 8192; i += nt) {
        int j = i & 7, lane = (i >> 3) & 63, ct = i >> 9;
        int cout = 16 * ct + (lane & 15);
        int m = 8 * (lane >> 4) + j;
        float inv = lg2[cout] * rsqrtf(lv2[cout] + BNEPS);
        af2[i] = f2bf(lw2[cout * NM + m] * inv);
    }
    // global-branch folded weights (fp32, exact)
    for (int i = tid; i < NC * NM; i += nt) {
        int c = i >> 5, m = i & 31;
        float gi1 = gg1[m] * rsqrtf(gv1[m] + BNEPS);
        gw1t[c * NM + m] = gw1[m * NC + c] * gi1;
        float gi2 = gg2[c] * rsqrtf(gv2[c] + BNEPS);
        gw2t[m * NC + c] = gw2[c * NM + m] * gi2;
    }
    for (int i = tid; i < NM; i += nt) {
        float inv = lg1[i] * rsqrtf(lv1[i] + BNEPS);
        b1f[i] = lb1[i] * inv + lbe1[i] - lm1[i] * inv;
        float gi = gg1[i] * rsqrtf(gv1[i] + BNEPS);
        gb1f[i] = gb1[i] * gi + gbe1[i] - gm1[i] * gi;
    }
    for (int i = tid; i < NC; i += nt) {
        float inv = lg2[i] * rsqrtf(lv2[i] + BNEPS);
        b2f[i] = lb2[i] * inv + lbe2[i] - lm2[i] * inv;
        float gi = gg2[i] * rsqrtf(gv2[i] + BNEPS);
        gb2f[i] = gb2[i] * gi + gbe2[i] - gm2[i] * gi;
    }
    for (int i = tid; i < NB * NC; i += nt) gmaxU[i] = 0u;  // below all floats
}

// ---------------- kernel B: conv1 (MFMA) + max + conv2 (MFMA) -> z ----------
// grid (NL/LT1=32, nbh), 256 thr.  Per block: full K=256 in 4 stages of 64c;
// h kept in regs -> LDS [l][m]; z = W2*h via MFMA, transposed through vt for
// 256B-contiguous bf16 stores to z[brel][cout][l].
__global__ __launch_bounds__(256, 4) void k_conv(
    const float4* __restrict__ x4, const float4* __restrict__ y4,
    const u16* __restrict__ af1, const u16* __restrict__ af2,
    const float* __restrict__ b1f, unsigned* __restrict__ gmaxU,
    u32* __restrict__ z2, int b_off) {
    __shared__ u16 vt[64 * LDW];      // 16.9KB: V stage, then z transpose buf
    __shared__ u16 hl[128 * HLW];     // 10.2KB: h[l][m] bf16
    __shared__ float cmax[256];
    int brel = blockIdx.y;
    int b    = b_off + brel;
    int l0   = blockIdx.x * LT1;
    int tid  = threadIdx.x;
    int w = tid >> 6, lane = tid & 63, g = lane >> 4, li = lane & 15;
    int hw = tid >> 5, lq = tid & 31;

    f32x4 acc[2][2];
#pragma unroll
    for (int mt = 0; mt < 2; ++mt)
#pragma unroll
        for (int t = 0; t < 2; ++t) {
            f32x4 zr = {0.f, 0.f, 0.f, 0.f};
            acc[mt][t] = zr;
        }

    for (int s = 0; s < 4; ++s) {
        // A-frags for this stage's two k-chunks (q = 2s, 2s+1)
        bf16x8 a1[2][2];
#pragma unroll
        for (int mt = 0; mt < 2; ++mt)
#pragma unroll
            for (int qq = 0; qq < 2; ++qq)
                a1[mt][qq] = *(const bf16x8*)(
                    af1 + (((mt * 8 + 2 * s + qq) * 64) + lane) * 8);

        // ---- stage 64c x 128l into vt (bf16, [c][l]) -----------------------
#pragma unroll
        for (int it = 0; it < 8; ++it) {
            int cc = it * 8 + hw;
            int c  = s * 64 + cc;
            size_t ridx = ((size_t)(b * NC + c)) * (NL / 4) + (l0 >> 2) + lq;
            float4 xv = x4[ridx];
            float4 yv = y4[ridx];
            uint2 wv;
            wv.x = pack2(xv.x + yv.x, xv.y + yv.y);
            wv.y = pack2(xv.z + yv.z, xv.w + yv.w);
            *(uint2*)&vt[cc * LDW + 4 * lq] = wv;
        }
        __syncthreads();

        // ---- MFMA: 2 k-chunks of 32 --------------------------------------
#pragma unroll
        for (int qq = 0; qq < 2; ++qq)
#pragma unroll
            for (int t = 0; t < 2; ++t) {
                int lcol = 32 * w + 16 * t + li;
                bf16x8 bf;
#pragma unroll
                for (int j = 0; j < 8; ++j)
                    bf[j] = (short)vt[(32 * qq + 8 * g + j) * LDW + lcol];
                acc[0][t] = __builtin_amdgcn_mfma_f32_16x16x32_bf16(
                    a1[0][qq], bf, acc[0][t], 0, 0, 0);
                acc[1][t] = __builtin_amdgcn_mfma_f32_16x16x32_bf16(
                    a1[1][qq], bf, acc[1][t], 0, 0, 0);
            }

        // ---- channel max over this stage's 64 c --------------------------
        {
            int cc = tid & 63, q4 = tid >> 6;
            int base = cc * LDW + 32 * q4;
            float mx = -3.402823466e38f;
#pragma unroll 8
            for (int l = 0; l < 32; ++l)
                mx = fmaxf(mx, bf2f(vt[base + l]));
            cmax[tid] = mx;
        }
        __syncthreads();   // cmax ready; vt free for next stage
        if (tid < 64) {
            float m0 = fmaxf(fmaxf(cmax[tid], cmax[tid + 64]),
                             fmaxf(cmax[tid + 128], cmax[tid + 192]));
            atomicMax(&gmaxU[b * NC + s * 64 + tid], f2u_mono(m0));
        }
    }

    // ---- h = relu(acc + b1) -> hl[l][m] bf16 -------------------------------
#pragma unroll
    for (int mt = 0; mt < 2; ++mt)
#pragma unroll
        for (int t = 0; t < 2; ++t) {
            int l  = 32 * w + 16 * t + li;
            int m0 = 16 * mt + 4 * g;
            float h0 = fmaxf(acc[mt][t][0] + b1f[m0 + 0], 0.f);
            float h1 = fmaxf(acc[mt][t][1] + b1f[m0 + 1], 0.f);
            float h2 = fmaxf(acc[mt][t][2] + b1f[m0 + 2], 0.f);
            float h3 = fmaxf(acc[mt][t][3] + b1f[m0 + 3], 0.f);
            uint2 st;
            st.x = pack2(h0, h1);
            st.y = pack2(h2, h3);
            *(uint2*)&hl[l * HLW + m0] = st;   // 80l+32mt+8g bytes: 8-aligned
        }
    __syncthreads();

    // ---- conv2: z = W2*h, 4 rounds of 64 couts, transpose via vt ----------
    for (int r = 0; r < 4; ++r) {
#pragma unroll
        for (int c4 = 0; c4 < 4; ++c4) {
            int ct = 4 * r + c4;
            bf16x8 a2 = *(const bf16x8*)(af2 + (ct * 64 + lane) * 8);
#pragma unroll
            for (int t = 0; t < 2; ++t) {
                int l = 32 * w + 16 * t + li;
                bf16x8 hb = *(const bf16x8*)&hl[l * HLW + 8 * g];  // 16B-aligned
                f32x4 zz = {0.f, 0.f, 0.f, 0.f};
                zz = __builtin_amdgcn_mfma_f32_16x16x32_bf16(a2, hb, zz, 0, 0, 0);
#pragma unroll
                for (int rr = 0; rr < 4; ++rr)
                    vt[(16 * c4 + 4 * g + rr) * LDW + l] = f2bf(zz[rr]);
            }
        }
        __syncthreads();
        // store 64 rows, 256B contiguous per row
#pragma unroll
        for (int i = 0; i < 16; ++i) {
            int row  = 16 * w + i;
            int cout = 64 * r + row;
            u32 v = *(const u32*)&vt[row * LDW + 2 * lane];
            z2[(((size_t)brel * NC + cout) * NL + l0) / 2 + lane] = v;
        }
        __syncthreads();
    }
}

// ---------------- kernel C: global branch (maxpool -> FC -> FC) -------------
__global__ __launch_bounds__(256) void k_global(
    const float* __restrict__ gw1t, const float* __restrict__ gb1f,
    const float* __restrict__ gw2t, const float* __restrict__ gb2f,
    const float* __restrict__ b2f, const unsigned* __restrict__ gmaxU,
    float* __restrict__ ac, int b_off) {
    __shared__ float smax[NC];
    __shared__ float g1[NM];
    int b = b_off + blockIdx.x;
    int t = threadIdx.x;
    smax[t] = u2f_mono(gmaxU[b * NC + t]);
    __syncthreads();
    if (t < NM) {
        float a = gb1f[t];
        for (int c = 0; c < NC; ++c) a = fmaf(gw1t[c * NM + t], smax[c], a);
        g1[t] = fmaxf(a, 0.f);
    }
    __syncthreads();
    float a = b2f[t] + gb2f[t];
#pragma unroll
    for (int m = 0; m < NM; ++m) a = fmaf(gw2t[m * NC + t], g1[m], a);
    ac[b * NC + t] = a;  // = b2f[c] + ga[b][c]
}

// ---------------- kernel D: streaming blend ---------------------------------
// grid nbh*64 blocks x 256 thr, 16 float4-iterations each; fully coalesced.
__global__ __launch_bounds__(256, 8) void k_blend(
    const float4* __restrict__ x4, const float4* __restrict__ y4,
    const uint2* __restrict__ z2, const float* __restrict__ ac,
    float4* __restrict__ out4, int b_off) {
    int t0     = blockIdx.x * 256 + threadIdx.x;
    int stride = gridDim.x * 256;
#pragma unroll 2
    for (int it = 0; it < 16; ++it) {
        int f = t0 + it * stride;              // local float4 index
        int brel = f >> 18;                    // NC*NL/4 = 2^18
        int c    = (f >> 10) & (NC - 1);       // NL/4 = 2^10
        size_t fg = ((size_t)b_off << 18) + f; // global float4 index
        float4 xv = x4[fg];
        float4 yv = y4[fg];
        uint2  zv = z2[f];
        float a = ac[(b_off + brel) * NC + c];
        float z0 = bf2f((u16)(zv.x & 0xffffu)) + a;
        float z1 = bf2f((u16)(zv.x >> 16)) + a;
        float z2v = bf2f((u16)(zv.y & 0xffffu)) + a;
        float z3 = bf2f((u16)(zv.y >> 16)) + a;
        float a0 = 1.f / (1.f + __expf(-z0));
        float a1 = 1.f / (1.f + __expf(-z1));
        float a2 = 1.f / (1.f + __expf(-z2v));
        float a3 = 1.f / (1.f + __expf(-z3));
        float4 o;
        float t;
        t = yv.x + a0 * (xv.x - yv.x); o.x = t + t;
        t = yv.y + a1 * (xv.y - yv.y); o.y = t + t;
        t = yv.z + a2 * (xv.z - yv.z); o.z = t + t;
        t = yv.w + a3 * (xv.w - yv.w); o.w = t + t;
        out4[fg] = o;
    }
}

extern "C" void kernel_launch(void* const* d_in, const int* in_sizes, int n_in,
                              void* d_out, int out_size, void* d_ws,
                              size_t ws_size, hipStream_t stream) {
    (void)in_sizes; (void)n_in; (void)out_size;
    const float* x = (const float*)d_in[0];
    const float* y = (const float*)d_in[1];
    float* ws  = (float*)d_ws;
    float* out = (float*)d_out;

    u16* af1   = (u16*)(ws + OFF_AF1);
    u16* af2   = (u16*)(ws + OFF_AF2);
    float* b1f  = ws + OFF_B1F;  float* b2f  = ws + OFF_B2F;
    float* gw1t = ws + OFF_GW1T; float* gb1f = ws + OFF_GB1F;
    float* gw2t = ws + OFF_GW2T; float* gb2f = ws + OFF_GB2F;
    float* ac   = ws + OFF_AC;
    unsigned* gmaxU = (unsigned*)(ws + OFF_GMAX);
    u32* z2 = (u32*)(ws + OFF_Z);

    k_fold<<<64, 256, 0, stream>>>(
        (const float*)d_in[2],  (const float*)d_in[3],  (const float*)d_in[4],
        (const float*)d_in[5],  (const float*)d_in[6],  (const float*)d_in[7],
        (const float*)d_in[8],  (const float*)d_in[9],  (const float*)d_in[10],
        (const float*)d_in[11], (const float*)d_in[12], (const float*)d_in[13],
        (const float*)d_in[14], (const float*)d_in[15], (const float*)d_in[16],
        (const float*)d_in[17], (const float*)d_in[18], (const float*)d_in[19],
        (const float*)d_in[20], (const float*)d_in[21], (const float*)d_in[22],
        (const float*)d_in[23], (const float*)d_in[24], (const float*)d_in[25],
        ws);

    // z buffer needs nbh*NC*NL*2 bytes beyond OFF_Z; fall back to 2 halves
    // if ws is too small (V2 proved ws_size >= 40.2MB).
    size_t need_full = ((size_t)OFF_Z + (size_t)NB * NC * NL / 2) * 4;
    int nbh = (ws_size >= need_full) ? NB : (NB / 2);

    for (int b0 = 0; b0 < NB; b0 += nbh) {
        k_conv<<<dim3(NL / LT1, nbh), 256, 0, stream>>>(
            (const float4*)x, (const float4*)y, af1, af2, b1f, gmaxU, z2, b0);
        k_global<<<nbh, 256, 0, stream>>>(
            gw1t, gb1f, gw2t, gb2f, b2f, gmaxU, ac, b0);
        k_blend<<<nbh * 64, 256, 0, stream>>>(
            (const float4*)x, (const float4*)y, (const uint2*)z2, ac,
            (float4*)out, b0);
    }
}